// Round 1
// baseline (1452.385 us; speedup 1.0000x reference)
//
#include <hip/hip_runtime.h>
#include <math.h>

#define Bsz 4096
#define T_STEPS 256
#define Fdim 32
#define Udim 64
#define G4 256            // 4*U
#define OUT_STEPS 24
#define ROWS 16           // batch rows per block
#define NBLK (Bsz / ROWS) // 256
#define NTHR 256
#define KTOT 96           // U + F  (hx layout: [0..63]=h, [64..95]=x)

// LDS: WQ[k*256 + u*4 + g] : k<64 -> U*[k][g*64+u], k>=64 -> W*[k-64][g*64+u]
//      hx[r*96 + 0..63]=h, [64..95]=x/pred
//      WdL[u*32 + c]
#define SMEM_FLOATS (KTOT * G4 + ROWS * KTOT + Udim * Fdim)

__device__ __forceinline__ float sigm(float v) { return 1.0f / (1.0f + __expf(-v)); }
__device__ __forceinline__ float tanh_fast(float v) {
    float a = fabsf(v);
    float e = __expf(-2.0f * a);          // in (0,1], no overflow
    float t = (1.0f - e) / (1.0f + e);
    return copysignf(t, v);
}

__global__ __launch_bounds__(NTHR, 1)
void lstm_kernel(const float* __restrict__ x,
                 const float* __restrict__ W1, const float* __restrict__ U1, const float* __restrict__ b1,
                 const float* __restrict__ W2, const float* __restrict__ U2, const float* __restrict__ b2,
                 const float* __restrict__ Wd, const float* __restrict__ bd,
                 float* __restrict__ out)
{
    extern __shared__ float smem[];
    float* WQ  = smem;                  // 24576 floats
    float* hx  = smem + KTOT * G4;      // 1536 floats
    float* WdL = hx + ROWS * KTOT;      // 2048 floats

    const int tid = threadIdx.x;
    const int u   = tid & 63;           // unit this thread owns
    const int r0  = (tid >> 6) * 4;     // 4 rows: r0..r0+3
    const int brow = blockIdx.x * ROWS;

    float bg1[4], bg2[4];
#pragma unroll
    for (int g = 0; g < 4; ++g) { bg1[g] = b1[g * Udim + u]; bg2[g] = b2[g * Udim + u]; }

    const int pr = tid >> 5;            // dense-phase rows pr, pr+8
    const int pc = tid & 31;            // dense-phase col
    const float bdv = bd[pc];

    // ---- stage-1 weights -> LDS (gate-quad packed) ----
    for (int idx = tid; idx < KTOT * G4; idx += NTHR) {
        int k = idx >> 8;
        int j = idx & 255;
        float v = (k < Udim) ? U1[k * G4 + j] : W1[(k - Udim) * G4 + j];
        WQ[k * 256 + (j & 63) * 4 + (j >> 6)] = v;
    }
    for (int idx = tid; idx < Udim * Fdim; idx += NTHR) WdL[idx] = Wd[idx];
    for (int idx = tid; idx < ROWS * Udim; idx += NTHR) {
        int rr = idx >> 6, uu = idx & 63;
        hx[rr * KTOT + uu] = 0.0f;
    }
    for (int idx = tid; idx < ROWS * Fdim; idx += NTHR) {
        int rr = idx >> 5, ff = idx & 31;
        hx[rr * KTOT + Udim + ff] = x[(size_t)(brow + rr) * (T_STEPS * Fdim) + ff];
    }

    float cst[4] = {0.f, 0.f, 0.f, 0.f};
    __syncthreads();

    const size_t xrow0 = (size_t)(brow + pr) * (T_STEPS * Fdim) + pc;
    const size_t xrow1 = (size_t)(brow + pr + 8) * (T_STEPS * Fdim) + pc;

    // ================= warmup: 256 steps of LSTM1 =================
    for (int t = 0; t < T_STEPS; ++t) {
        float xp0 = 0.f, xp1 = 0.f;
        if (t + 1 < T_STEPS) {          // prefetch next x into regs
            xp0 = x[xrow0 + (size_t)(t + 1) * Fdim];
            xp1 = x[xrow1 + (size_t)(t + 1) * Fdim];
        }

        float z[4][4];
#pragma unroll
        for (int r = 0; r < 4; ++r)
#pragma unroll
            for (int g = 0; g < 4; ++g) z[r][g] = bg1[g];

        for (int kq = 0; kq < KTOT; kq += 4) {
            float4 hv[4];
#pragma unroll
            for (int r = 0; r < 4; ++r)
                hv[r] = *(const float4*)&hx[(r0 + r) * KTOT + kq];   // broadcast b128
#pragma unroll
            for (int kk = 0; kk < 4; ++kk) {
                float4 w = *(const float4*)&WQ[(kq + kk) * 256 + u * 4]; // lane-strided b128
#pragma unroll
                for (int r = 0; r < 4; ++r) {
                    float hvk = ((const float*)&hv[r])[kk];
                    z[r][0] = fmaf(hvk, w.x, z[r][0]);
                    z[r][1] = fmaf(hvk, w.y, z[r][1]);
                    z[r][2] = fmaf(hvk, w.z, z[r][2]);
                    z[r][3] = fmaf(hvk, w.w, z[r][3]);
                }
            }
        }

        float hn[4];
#pragma unroll
        for (int r = 0; r < 4; ++r) {
            float ig = sigm(z[r][0]);
            float fg = sigm(z[r][1]);
            float gg = tanh_fast(z[r][2]);
            float og = sigm(z[r][3]);
            cst[r] = fg * cst[r] + ig * gg;
            hn[r] = og * tanh_fast(cst[r]);
        }
        __syncthreads();                 // all reads of hx for step t done
#pragma unroll
        for (int r = 0; r < 4; ++r) hx[(r0 + r) * KTOT + u] = hn[r];
        if (t + 1 < T_STEPS) {
            hx[pr * KTOT + Udim + pc] = xp0;
            hx[(pr + 8) * KTOT + Udim + pc] = xp1;
        }
        __syncthreads();                 // hx ready for step t+1
    }

    // ================= pred0 = h @ Wd + bd =================
#pragma unroll
    for (int rr = 0; rr < 2; ++rr) {
        int r = pr + rr * 8;
        float acc = bdv;
        for (int uu = 0; uu < Udim; uu += 4) {
            float4 h4 = *(const float4*)&hx[r * KTOT + uu];
            acc = fmaf(h4.x, WdL[(uu + 0) * Fdim + pc], acc);
            acc = fmaf(h4.y, WdL[(uu + 1) * Fdim + pc], acc);
            acc = fmaf(h4.z, WdL[(uu + 2) * Fdim + pc], acc);
            acc = fmaf(h4.w, WdL[(uu + 3) * Fdim + pc], acc);
        }
        out[(size_t)(brow + r) * (OUT_STEPS * Fdim) + pc] = acc;
        hx[r * KTOT + Udim + pc] = acc;  // feed back as next input (disjoint from h-part reads)
    }

    // ---- stage-2 weights -> LDS (stage-1 reads all completed before last barrier) ----
    for (int idx = tid; idx < KTOT * G4; idx += NTHR) {
        int k = idx >> 8;
        int j = idx & 255;
        float v = (k < Udim) ? U2[k * G4 + j] : W2[(k - Udim) * G4 + j];
        WQ[k * 256 + (j & 63) * 4 + (j >> 6)] = v;
    }
    __syncthreads();

    // ================= decode: 23 steps of LSTM2 + dense =================
    for (int s = 1; s < OUT_STEPS; ++s) {
        float z[4][4];
#pragma unroll
        for (int r = 0; r < 4; ++r)
#pragma unroll
            for (int g = 0; g < 4; ++g) z[r][g] = bg2[g];

        for (int kq = 0; kq < KTOT; kq += 4) {
            float4 hv[4];
#pragma unroll
            for (int r = 0; r < 4; ++r)
                hv[r] = *(const float4*)&hx[(r0 + r) * KTOT + kq];
#pragma unroll
            for (int kk = 0; kk < 4; ++kk) {
                float4 w = *(const float4*)&WQ[(kq + kk) * 256 + u * 4];
#pragma unroll
                for (int r = 0; r < 4; ++r) {
                    float hvk = ((const float*)&hv[r])[kk];
                    z[r][0] = fmaf(hvk, w.x, z[r][0]);
                    z[r][1] = fmaf(hvk, w.y, z[r][1]);
                    z[r][2] = fmaf(hvk, w.z, z[r][2]);
                    z[r][3] = fmaf(hvk, w.w, z[r][3]);
                }
            }
        }

        float hn[4];
#pragma unroll
        for (int r = 0; r < 4; ++r) {
            float ig = sigm(z[r][0]);
            float fg = sigm(z[r][1]);
            float gg = tanh_fast(z[r][2]);
            float og = sigm(z[r][3]);
            cst[r] = fg * cst[r] + ig * gg;
            hn[r] = og * tanh_fast(cst[r]);
        }
        __syncthreads();
#pragma unroll
        for (int r = 0; r < 4; ++r) hx[(r0 + r) * KTOT + u] = hn[r];
        __syncthreads();

#pragma unroll
        for (int rr = 0; rr < 2; ++rr) {
            int r = pr + rr * 8;
            float acc = bdv;
            for (int uu = 0; uu < Udim; uu += 4) {
                float4 h4 = *(const float4*)&hx[r * KTOT + uu];
                acc = fmaf(h4.x, WdL[(uu + 0) * Fdim + pc], acc);
                acc = fmaf(h4.y, WdL[(uu + 1) * Fdim + pc], acc);
                acc = fmaf(h4.z, WdL[(uu + 2) * Fdim + pc], acc);
                acc = fmaf(h4.w, WdL[(uu + 3) * Fdim + pc], acc);
            }
            out[(size_t)(brow + r) * (OUT_STEPS * Fdim) + s * Fdim + pc] = acc;
            hx[r * KTOT + Udim + pc] = acc;
        }
        __syncthreads();
    }
}

extern "C" void kernel_launch(void* const* d_in, const int* in_sizes, int n_in,
                              void* d_out, int out_size, void* d_ws, size_t ws_size,
                              hipStream_t stream) {
    (void)in_sizes; (void)n_in; (void)out_size; (void)d_ws; (void)ws_size;
    const float* x  = (const float*)d_in[0];
    const float* W1 = (const float*)d_in[1];
    const float* U1 = (const float*)d_in[2];
    const float* b1 = (const float*)d_in[3];
    const float* W2 = (const float*)d_in[4];
    const float* U2 = (const float*)d_in[5];
    const float* b2 = (const float*)d_in[6];
    const float* Wd = (const float*)d_in[7];
    const float* bd = (const float*)d_in[8];
    float* out = (float*)d_out;

    static bool attr_set = false;       // idempotent host-side attr, not a stream op
    if (!attr_set) {
        hipFuncSetAttribute((const void*)lstm_kernel,
                            hipFuncAttributeMaxDynamicSharedMemorySize,
                            SMEM_FLOATS * 4);
        attr_set = true;
    }

    lstm_kernel<<<dim3(NBLK), dim3(NTHR), SMEM_FLOATS * 4, stream>>>(
        x, W1, U1, b1, W2, U2, b2, Wd, bd, out);
}

// Round 2
// 441.507 us; speedup vs baseline: 3.2896x; 3.2896x over previous
//
#include <hip/hip_runtime.h>
#include <math.h>

#define T_STEPS 256
#define Fdim 32
#define Udim 64
#define G4 256            // 4*U
#define OUT_STEPS 24
#define ROWS 16           // batch rows per block (= MFMA M)
#define NBLK 256          // 4096 / 16
#define NTHR 512          // 8 waves
#define KTOT 96           // U + F
#define HXS 104           // bf16 row stride (96 + 8 pad)
#define ZS  260           // fp32 z row stride (256 + 4 pad)

typedef __attribute__((ext_vector_type(8))) short short8;   // 8 bf16 = 4 VGPR
typedef __attribute__((ext_vector_type(4))) float f32x4;

__device__ __forceinline__ short f2bf(float f) {
    union { float f; unsigned u; } v; v.f = f;
    unsigned r = v.u + 0x7FFFu + ((v.u >> 16) & 1u);   // RNE
    return (short)(r >> 16);
}
__device__ __forceinline__ float bf2f(short s) {
    union { unsigned u; float f; } v; v.u = ((unsigned)(unsigned short)s) << 16;
    return v.f;
}
__device__ __forceinline__ float sigm(float v) { return 1.0f / (1.0f + __expf(-v)); }
__device__ __forceinline__ float tanh_fast(float v) {
    float a = fabsf(v);
    float e = __expf(-2.0f * a);          // in (0,1], no overflow
    float t = (1.0f - e) / (1.0f + e);
    return copysignf(t, v);
}

// LSTM via MFMA: per step  z[16x256] = hx_bf16[16x96] @ Wall_bf16[96x256] + b
// A-frag (16x16x32 bf16): lane l holds A[m=l&15][k=(l>>4)*8+j], j=0..7
// B-frag:                 lane l holds B[k=(l>>4)*8+j][n=l&15]
// C/D:                    lane l holds D[row=(l>>4)*4+reg][col=l&15]   (m89-verified)
__global__ __launch_bounds__(NTHR, 1)
void lstm_mfma(const float* __restrict__ x,
               const float* __restrict__ W1, const float* __restrict__ U1, const float* __restrict__ b1,
               const float* __restrict__ W2, const float* __restrict__ U2, const float* __restrict__ b2,
               const float* __restrict__ Wd, const float* __restrict__ bd,
               float* __restrict__ out)
{
    __shared__ __align__(16) short hx[ROWS][HXS];   // bf16 bits: [0..63]=h, [64..95]=x/pred
    __shared__ float zbuf[ROWS][ZS];                // gate pre-activations, fp32
    __shared__ float WdL[Udim * Fdim];              // dense weights, fp32

    const int tid = threadIdx.x;
    const int l   = tid & 63;         // lane in wave
    const int w   = tid >> 6;         // wave 0..7: owns gate-cols [w*32, w*32+32)
    const int q   = l >> 4;           // quad
    const int m   = l & 15;
    const int brow = blockIdx.x * ROWS;

    // ---- stage both weight sets as register-resident B-fragments ----
    short8 wf1[3][2], wf2[3][2];      // [kt][nt]
    float bias1[2], bias2[2];
#pragma unroll
    for (int kt = 0; kt < 3; ++kt)
#pragma unroll
        for (int nt = 0; nt < 2; ++nt) {
            const int n = w * 32 + nt * 16 + m;
            short8 fa, fb;
#pragma unroll
            for (int j = 0; j < 8; ++j) {
                const int k = kt * 32 + q * 8 + j;
                float v1 = (k < Udim) ? U1[k * G4 + n] : W1[(k - Udim) * G4 + n];
                float v2 = (k < Udim) ? U2[k * G4 + n] : W2[(k - Udim) * G4 + n];
                fa[j] = f2bf(v1);
                fb[j] = f2bf(v2);
            }
            wf1[kt][nt] = fa;
            wf2[kt][nt] = fb;
        }
#pragma unroll
    for (int nt = 0; nt < 2; ++nt) {
        const int n = w * 32 + nt * 16 + m;
        bias1[nt] = b1[n];
        bias2[nt] = b2[n];
    }

    // elementwise ownership: thread -> unit u, rows rb and rb+8; c-state fp32 in regs
    const int u  = tid & 63;
    const int rb = tid >> 6;          // 0..7
    float cst[2] = {0.f, 0.f};

    // staging / dense ownership: one (row, col) per thread
    const int sr = tid >> 5;          // 0..15
    const int sc = tid & 31;
    const float bdv = bd[sc];

    for (int idx = tid; idx < Udim * Fdim; idx += NTHR) WdL[idx] = Wd[idx];
    hx[rb][u] = 0;                    // h init (rows 0..7)
    hx[rb + 8][u] = 0;                //        (rows 8..15)
    hx[sr][Udim + sc] = f2bf(x[(size_t)(brow + sr) * (T_STEPS * Fdim) + sc]);  // x_0
    __syncthreads();

    const size_t xbase = (size_t)(brow + sr) * (T_STEPS * Fdim) + sc;

    // ================= warmup: 256 steps of LSTM1 =================
    for (int t = 0; t < T_STEPS; ++t) {
        float xp = 0.f;
        if (t + 1 < T_STEPS) xp = x[xbase + (size_t)(t + 1) * Fdim];  // prefetch

        short8 af[3];
#pragma unroll
        for (int kt = 0; kt < 3; ++kt)
            af[kt] = *(const short8*)&hx[m][kt * 32 + q * 8];

        f32x4 acc[2];
#pragma unroll
        for (int nt = 0; nt < 2; ++nt) {
            acc[nt][0] = bias1[nt]; acc[nt][1] = bias1[nt];
            acc[nt][2] = bias1[nt]; acc[nt][3] = bias1[nt];
        }
#pragma unroll
        for (int nt = 0; nt < 2; ++nt)
#pragma unroll
            for (int kt = 0; kt < 3; ++kt)
                acc[nt] = __builtin_amdgcn_mfma_f32_16x16x32_bf16(af[kt], wf1[kt][nt], acc[nt], 0, 0, 0);

#pragma unroll
        for (int nt = 0; nt < 2; ++nt)
#pragma unroll
            for (int reg = 0; reg < 4; ++reg)
                zbuf[q * 4 + reg][w * 32 + nt * 16 + m] = acc[nt][reg];
        __syncthreads();              // z complete; all A-reads of step t complete

        float hn[2];
#pragma unroll
        for (int jj = 0; jj < 2; ++jj) {
            const int r = rb + jj * 8;
            float zi = zbuf[r][u], zf = zbuf[r][64 + u];
            float zg = zbuf[r][128 + u], zo = zbuf[r][192 + u];
            float ig = sigm(zi), fg = sigm(zf);
            float gg = tanh_fast(zg), og = sigm(zo);
            cst[jj] = fg * cst[jj] + ig * gg;
            hn[jj]  = og * tanh_fast(cst[jj]);
        }
        hx[rb][u]     = f2bf(hn[0]);
        hx[rb + 8][u] = f2bf(hn[1]);
        if (t + 1 < T_STEPS) hx[sr][Udim + sc] = f2bf(xp);
        __syncthreads();              // hx ready for step t+1
    }

    // ================= pred0 = h @ Wd + bd (fp32) =================
    {
        float acc = bdv;
#pragma unroll
        for (int kb = 0; kb < 8; ++kb) {
            short8 h8 = *(const short8*)&hx[sr][kb * 8];
#pragma unroll
            for (int j = 0; j < 8; ++j)
                acc = fmaf(bf2f(h8[j]), WdL[(kb * 8 + j) * Fdim + sc], acc);
        }
        out[(size_t)(brow + sr) * (OUT_STEPS * Fdim) + sc] = acc;
        hx[sr][Udim + sc] = f2bf(acc);   // feed back as next input
    }
    __syncthreads();

    // ================= decode: 23 steps of LSTM2 + dense =================
    for (int s = 1; s < OUT_STEPS; ++s) {
        short8 af[3];
#pragma unroll
        for (int kt = 0; kt < 3; ++kt)
            af[kt] = *(const short8*)&hx[m][kt * 32 + q * 8];

        f32x4 acc[2];
#pragma unroll
        for (int nt = 0; nt < 2; ++nt) {
            acc[nt][0] = bias2[nt]; acc[nt][1] = bias2[nt];
            acc[nt][2] = bias2[nt]; acc[nt][3] = bias2[nt];
        }
#pragma unroll
        for (int nt = 0; nt < 2; ++nt)
#pragma unroll
            for (int kt = 0; kt < 3; ++kt)
                acc[nt] = __builtin_amdgcn_mfma_f32_16x16x32_bf16(af[kt], wf2[kt][nt], acc[nt], 0, 0, 0);

#pragma unroll
        for (int nt = 0; nt < 2; ++nt)
#pragma unroll
            for (int reg = 0; reg < 4; ++reg)
                zbuf[q * 4 + reg][w * 32 + nt * 16 + m] = acc[nt][reg];
        __syncthreads();

        float hn[2];
#pragma unroll
        for (int jj = 0; jj < 2; ++jj) {
            const int r = rb + jj * 8;
            float zi = zbuf[r][u], zf = zbuf[r][64 + u];
            float zg = zbuf[r][128 + u], zo = zbuf[r][192 + u];
            float ig = sigm(zi), fg = sigm(zf);
            float gg = tanh_fast(zg), og = sigm(zo);
            cst[jj] = fg * cst[jj] + ig * gg;
            hn[jj]  = og * tanh_fast(cst[jj]);
        }
        hx[rb][u]     = f2bf(hn[0]);
        hx[rb + 8][u] = f2bf(hn[1]);
        __syncthreads();              // h ready for dense

        float dacc = bdv;
#pragma unroll
        for (int kb = 0; kb < 8; ++kb) {
            short8 h8 = *(const short8*)&hx[sr][kb * 8];
#pragma unroll
            for (int j = 0; j < 8; ++j)
                dacc = fmaf(bf2f(h8[j]), WdL[(kb * 8 + j) * Fdim + sc], dacc);
        }
        out[(size_t)(brow + sr) * (OUT_STEPS * Fdim) + s * Fdim + sc] = dacc;
        hx[sr][Udim + sc] = f2bf(dacc);  // pred feedback (x-part; disjoint from h-part reads)
        __syncthreads();
    }
}

extern "C" void kernel_launch(void* const* d_in, const int* in_sizes, int n_in,
                              void* d_out, int out_size, void* d_ws, size_t ws_size,
                              hipStream_t stream) {
    (void)in_sizes; (void)n_in; (void)out_size; (void)d_ws; (void)ws_size;
    const float* x  = (const float*)d_in[0];
    const float* W1 = (const float*)d_in[1];
    const float* U1 = (const float*)d_in[2];
    const float* b1 = (const float*)d_in[3];
    const float* W2 = (const float*)d_in[4];
    const float* U2 = (const float*)d_in[5];
    const float* b2 = (const float*)d_in[6];
    const float* Wd = (const float*)d_in[7];
    const float* bd = (const float*)d_in[8];
    float* out = (float*)d_out;

    lstm_mfma<<<dim3(NBLK), dim3(NTHR), 0, stream>>>(
        x, W1, U1, b1, W2, U2, b2, Wd, bd, out);
}

// Round 3
// 360.099 us; speedup vs baseline: 4.0333x; 1.2261x over previous
//
#include <hip/hip_runtime.h>
#include <math.h>

#define T_STEPS 256
#define Fdim 32
#define Udim 64
#define G4 256            // 4*U
#define OUT_STEPS 24
#define ROWS 16           // batch rows per block (= MFMA N now)
#define NBLK 256          // 4096 / 16
#define NTHR 512          // 8 waves
#define HXS 104           // bf16 row stride (96 + 8 pad)

typedef __attribute__((ext_vector_type(8))) short short8;   // 8 bf16 = 4 VGPR
typedef __attribute__((ext_vector_type(4))) float f32x4;

__device__ __forceinline__ short f2bf(float f) {
    union { float f; unsigned u; } v; v.f = f;
    unsigned r = v.u + 0x7FFFu + ((v.u >> 16) & 1u);   // RNE
    return (short)(r >> 16);
}
__device__ __forceinline__ float bf2f(short s) {
    union { unsigned u; float f; } v; v.u = ((unsigned)(unsigned short)s) << 16;
    return v.f;
}
__device__ __forceinline__ float frcp(float v) { return __builtin_amdgcn_rcpf(v); }
__device__ __forceinline__ float sigm(float v) { return frcp(1.0f + __expf(-v)); }
__device__ __forceinline__ float tanh_fast(float v) {
    float a = fabsf(v);
    float r = 1.0f - 2.0f * frcp(1.0f + __expf(2.0f * a));  // tanh(a), a>=0; exp overflow -> inf -> rcp=0 -> 1
    return copysignf(r, v);
}

// z^T = Wt[256x96] @ hx^T[96x16], gate rows packed as r = unit*4 + gate.
// A-frag (16x16x32): lane l holds A[m=l&15][k=(l>>4)*8+j]  -> static weights in VGPRs
// B-frag:            lane l holds B[k=(l>>4)*8+j][n=l&15]  -> reads hx[n][k] contiguously (ds_read_b128)
// C/D:               lane l holds D[row=(l>>4)*4+reg][col=l&15]
//   => row = q*4+reg in tile T covers unit = T*4+q, gate = reg: all 4 gates of one
//      (unit, batchrow=m) land in one lane's 4 acc regs. No z LDS round-trip.
__global__ __launch_bounds__(NTHR, 1)
void lstm_mfma_t(const float* __restrict__ x,
                 const float* __restrict__ W1, const float* __restrict__ U1, const float* __restrict__ b1,
                 const float* __restrict__ W2, const float* __restrict__ U2, const float* __restrict__ b2,
                 const float* __restrict__ Wd, const float* __restrict__ bd,
                 float* __restrict__ out)
{
    __shared__ __align__(16) short hxb[2][ROWS][HXS]; // bf16 bits: [0..63]=h, [64..95]=x/pred (ping-pong)
    __shared__ float WdL[Udim * Fdim];                // dense weights, fp32

    const int tid = threadIdx.x;
    const int l   = tid & 63;         // lane
    const int w   = tid >> 6;         // wave 0..7: owns gate-row tiles 2w, 2w+1 (units 8w..8w+7)
    const int q   = l >> 4;           // quad
    const int m   = l & 15;           // batch row (B col / D col)
    const int brow = blockIdx.x * ROWS;

    // ---- stage both weight sets as register-resident A-fragments (gate-interleaved rows) ----
    short8 wa1[2][3], wa2[2][3];      // [nt][kt]
    float bs1[2][4], bs2[2][4];       // bias per (nt, gate) for this lane's D rows
#pragma unroll
    for (int nt = 0; nt < 2; ++nt) {
        const int tile = w * 2 + nt;
        const int unit_a = tile * 4 + (m >> 2);   // A-frag row m -> (unit, gate)
        const int gate_a = m & 3;
        const int col = gate_a * 64 + unit_a;     // column in original [4U] gate layout
#pragma unroll
        for (int kt = 0; kt < 3; ++kt) {
            short8 fa, fb;
#pragma unroll
            for (int j = 0; j < 8; ++j) {
                const int k = kt * 32 + q * 8 + j;
                float v1 = (k < Udim) ? U1[k * G4 + col] : W1[(k - Udim) * G4 + col];
                float v2 = (k < Udim) ? U2[k * G4 + col] : W2[(k - Udim) * G4 + col];
                fa[j] = f2bf(v1);
                fb[j] = f2bf(v2);
            }
            wa1[nt][kt] = fa;
            wa2[nt][kt] = fb;
        }
        const int unit_d = tile * 4 + q;          // D rows q*4+reg -> unit_d, gate=reg
#pragma unroll
        for (int g = 0; g < 4; ++g) {
            bs1[nt][g] = b1[g * 64 + unit_d];
            bs2[nt][g] = b2[g * 64 + unit_d];
        }
    }

    // staging / dense ownership: one (row, col) per thread
    const int sr = tid >> 5;          // 0..15
    const int sc = tid & 31;
    const float bdv = bd[sc];

    for (int idx = tid; idx < Udim * Fdim; idx += NTHR) WdL[idx] = Wd[idx];
    {   // init buf0: h = 0, x = x_0
        const int r8 = tid >> 6, u = tid & 63;
        hxb[0][r8][u] = 0;
        hxb[0][r8 + 8][u] = 0;
        hxb[0][sr][Udim + sc] = f2bf(x[(size_t)(brow + sr) * (T_STEPS * Fdim) + sc]);
    }
    float cst[2] = {0.f, 0.f};        // fp32 cell state, one per nt tile
    __syncthreads();

    const size_t xbase = (size_t)(brow + sr) * (T_STEPS * Fdim) + sc;

    // ================= warmup: 256 steps of LSTM1, 1 barrier/step =================
#pragma unroll 2
    for (int t = 0; t < T_STEPS; ++t) {
        const int p = t & 1;
        float xp = 0.f;
        if (t + 1 < T_STEPS) xp = x[xbase + (size_t)(t + 1) * Fdim];  // prefetch

        short8 bfv[3];
#pragma unroll
        for (int kt = 0; kt < 3; ++kt)
            bfv[kt] = *(const short8*)&hxb[p][m][kt * 32 + q * 8];

        f32x4 acc[2];
#pragma unroll
        for (int nt = 0; nt < 2; ++nt)
#pragma unroll
            for (int g = 0; g < 4; ++g) acc[nt][g] = bs1[nt][g];
#pragma unroll
        for (int nt = 0; nt < 2; ++nt)
#pragma unroll
            for (int kt = 0; kt < 3; ++kt)
                acc[nt] = __builtin_amdgcn_mfma_f32_16x16x32_bf16(wa1[nt][kt], bfv[kt], acc[nt], 0, 0, 0);

#pragma unroll
        for (int nt = 0; nt < 2; ++nt) {
            float ig = sigm(acc[nt][0]);
            float fg = sigm(acc[nt][1]);
            float gg = tanh_fast(acc[nt][2]);
            float og = sigm(acc[nt][3]);
            cst[nt] = fg * cst[nt] + ig * gg;
            float hn = og * tanh_fast(cst[nt]);
            hxb[1 - p][m][(w * 2 + nt) * 4 + q] = f2bf(hn);
        }
        if (t + 1 < T_STEPS) hxb[1 - p][sr][Udim + sc] = f2bf(xp);
        __syncthreads();
    }

    // ================= pred0 = h @ Wd + bd (h in buf0) =================
    {
        float acc = bdv;
#pragma unroll
        for (int kb = 0; kb < 8; ++kb) {
            short8 h8 = *(const short8*)&hxb[0][sr][kb * 8];
#pragma unroll
            for (int j = 0; j < 8; ++j)
                acc = fmaf(bf2f(h8[j]), WdL[(kb * 8 + j) * Fdim + sc], acc);
        }
        out[(size_t)(brow + sr) * (OUT_STEPS * Fdim) + sc] = acc;
        hxb[0][sr][Udim + sc] = f2bf(acc);   // x-part write, disjoint from h-part reads above
    }
    __syncthreads();

    // ================= decode: 23 steps of LSTM2 + dense =================
    int dp = 0;
    for (int s = 1; s < OUT_STEPS; ++s) {
        short8 bfv[3];
#pragma unroll
        for (int kt = 0; kt < 3; ++kt)
            bfv[kt] = *(const short8*)&hxb[dp][m][kt * 32 + q * 8];

        f32x4 acc[2];
#pragma unroll
        for (int nt = 0; nt < 2; ++nt)
#pragma unroll
            for (int g = 0; g < 4; ++g) acc[nt][g] = bs2[nt][g];
#pragma unroll
        for (int nt = 0; nt < 2; ++nt)
#pragma unroll
            for (int kt = 0; kt < 3; ++kt)
                acc[nt] = __builtin_amdgcn_mfma_f32_16x16x32_bf16(wa2[nt][kt], bfv[kt], acc[nt], 0, 0, 0);

#pragma unroll
        for (int nt = 0; nt < 2; ++nt) {
            float ig = sigm(acc[nt][0]);
            float fg = sigm(acc[nt][1]);
            float gg = tanh_fast(acc[nt][2]);
            float og = sigm(acc[nt][3]);
            cst[nt] = fg * cst[nt] + ig * gg;
            float hn = og * tanh_fast(cst[nt]);
            hxb[1 - dp][m][(w * 2 + nt) * 4 + q] = f2bf(hn);
        }
        __syncthreads();              // h ready for dense

        float dacc = bdv;
#pragma unroll
        for (int kb = 0; kb < 8; ++kb) {
            short8 h8 = *(const short8*)&hxb[1 - dp][sr][kb * 8];
#pragma unroll
            for (int j = 0; j < 8; ++j)
                dacc = fmaf(bf2f(h8[j]), WdL[(kb * 8 + j) * Fdim + sc], dacc);
        }
        out[(size_t)(brow + sr) * (OUT_STEPS * Fdim) + s * Fdim + sc] = dacc;
        hxb[1 - dp][sr][Udim + sc] = f2bf(dacc);  // pred feedback
        __syncthreads();
        dp = 1 - dp;
    }
}

extern "C" void kernel_launch(void* const* d_in, const int* in_sizes, int n_in,
                              void* d_out, int out_size, void* d_ws, size_t ws_size,
                              hipStream_t stream) {
    (void)in_sizes; (void)n_in; (void)out_size; (void)d_ws; (void)ws_size;
    const float* x  = (const float*)d_in[0];
    const float* W1 = (const float*)d_in[1];
    const float* U1 = (const float*)d_in[2];
    const float* b1 = (const float*)d_in[3];
    const float* W2 = (const float*)d_in[4];
    const float* U2 = (const float*)d_in[5];
    const float* b2 = (const float*)d_in[6];
    const float* Wd = (const float*)d_in[7];
    const float* bd = (const float*)d_in[8];
    float* out = (float*)d_out;

    lstm_mfma_t<<<dim3(NBLK), dim3(NTHR), 0, stream>>>(
        x, W1, U1, b1, W2, U2, b2, Wd, bd, out);
}